// Round 6
// baseline (7052.129 us; speedup 1.0000x reference)
//
#include <hip/hip_runtime.h>
#include <math.h>

typedef _Float16 f16;
typedef _Float16 f16x8 __attribute__((ext_vector_type(8)));
typedef float f32x4 __attribute__((ext_vector_type(4)));

namespace {

constexpr int NT = 512;     // 8 waves, 1 block/CU
constexpr int M  = 128;     // agents per block
constexpr int HORIZON = 64;

__device__ __forceinline__ void mfma3(f32x4& acc, f16x8 ah, f16x8 al, f16x8 bh, f16x8 bl)
{
    acc = __builtin_amdgcn_mfma_f32_16x16x32_f16(ah, bh, acc, 0, 0, 0);
    acc = __builtin_amdgcn_mfma_f32_16x16x32_f16(al, bh, acc, 0, 0, 0);
    acc = __builtin_amdgcn_mfma_f32_16x16x32_f16(ah, bl, acc, 0, 0, 0);
}

// fetch this wave's B-fragment fp32s for one 32-K chunk (32 dwords/thread)
#define FETCH_B(Wp, kc, Fv) do {                                             \
    _Pragma("unroll")                                                        \
    for (int _nt = 0; _nt < 4; ++_nt) {                                      \
        const float* _p = (Wp) + ((kc)*32 + q*8)*256 + 64*cq + 16*_nt + lr;  \
        _Pragma("unroll")                                                    \
        for (int _j = 0; _j < 8; ++_j) (Fv)[_nt*8 + _j] = _p[_j*256];        \
    }                                                                        \
} while (0)

// convert prefetched fp32 B-frags to f16 hi/lo register fragments
#define CONV_B(Fv, bhv, blv) do {                                            \
    _Pragma("unroll")                                                        \
    for (int _nt = 0; _nt < 4; ++_nt) {                                      \
        _Pragma("unroll")                                                    \
        for (int _j = 0; _j < 8; ++_j) {                                     \
            float _v = (Fv)[_nt*8 + _j];                                     \
            f16 _h = (f16)_v;                                                \
            (bhv)[_nt][_j] = _h;                                             \
            (blv)[_nt][_j] = (f16)(_v - (float)_h);                          \
        }                                                                    \
    }                                                                        \
} while (0)

// relu + hi/lo split of acc tile into swizzled hA
#define WRITEBACK_ACC() do {                                                 \
    _Pragma("unroll")                                                        \
    for (int _mt = 0; _mt < 4; ++_mt) {                                      \
      _Pragma("unroll")                                                      \
      for (int _nt = 0; _nt < 4; ++_nt) {                                    \
        _Pragma("unroll")                                                    \
        for (int _r = 0; _r < 4; ++_r) {                                     \
            float _h = fmaxf(acc[_mt][_nt][_r], 0.f);                        \
            f16 _hi = (f16)_h;                                               \
            f16 _lo = (f16)(_h - (float)_hi);                                \
            int _row = 64*rh + 16*_mt + 4*q + _r;                            \
            int _col = 64*cq + 16*_nt + lr;                                  \
            int _off = _row*256 + (((_col >> 3) ^ (_row & 31)) << 3) + (_col & 7); \
            hA_hi[_off] = _hi;                                               \
            hA_lo[_off] = _lo;                                               \
        }                                                                    \
      }                                                                      \
    }                                                                        \
} while (0)

#define INIT_ACC(brv) do {                                                   \
    _Pragma("unroll")                                                        \
    for (int _mt = 0; _mt < 4; ++_mt)                                        \
      _Pragma("unroll")                                                      \
      for (int _nt = 0; _nt < 4; ++_nt)                                      \
        acc[_mt][_nt] = (f32x4){(brv)[_nt], (brv)[_nt], (brv)[_nt], (brv)[_nt]}; \
} while (0)

// observation write for agent thread t (< M): 32 f16 hi/lo, stride-40 rows
#define OBS_WRITE() do {                                                     \
    float _o[32];                                                            \
    float _dx0 = px - 1.75f, _dy0 = py - 1.75f;                              \
    float _dx1 = px - 1.75f, _dy1 = py - 3.75f;                              \
    float _dx2 = px - 3.75f, _dy2 = py - 2.00f;                              \
    _o[0] = px*0.1f;        _o[1] = py*0.1f;                                 \
    _o[2] = (4.f-px)*0.1f;  _o[3] = (3.f-py)*0.1f;                           \
    _o[4] = -_dx0*0.1f;     _o[5] = -_dy0*0.1f;                              \
    _o[6] = -_dx1*0.1f;     _o[7] = -_dy1*0.1f;                              \
    _o[8] = -_dx2*0.1f;     _o[9] = -_dy2*0.1f;                              \
    _o[10] = sqrtf(_dx0*_dx0+_dy0*_dy0+1e-9f) - 0.38f;                       \
    _o[11] = sqrtf(_dx1*_dx1+_dy1*_dy1+1e-9f) - 0.42f;                       \
    _o[12] = sqrtf(_dx2*_dx2+_dy2*_dy2+1e-9f) - 0.34f;                       \
    _Pragma("unroll")                                                        \
    for (int _k = 13; _k < 32; ++_k) _o[_k] = 0.f;                           \
    _Pragma("unroll")                                                        \
    for (int _c = 0; _c < 4; ++_c) {                                         \
        f16x8 _hi, _lo;                                                      \
        _Pragma("unroll")                                                    \
        for (int _j = 0; _j < 8; ++_j) {                                     \
            float _v = _o[_c*8 + _j];                                        \
            f16 _h = (f16)_v;                                                \
            _hi[_j] = _h; _lo[_j] = (f16)(_v - (float)_h);                   \
        }                                                                    \
        *(f16x8*)(hA_hi + t*40 + _c*8) = _hi;                                \
        *(f16x8*)(hA_lo + t*40 + _c*8) = _lo;                                \
    }                                                                        \
} while (0)

__global__ __launch_bounds__(NT, 2)
void rollout_kernel(const float* __restrict__ pos0, const float* __restrict__ wind,
                    const float* __restrict__ w1, const float* __restrict__ b1,
                    const float* __restrict__ w2, const float* __restrict__ b2,
                    const float* __restrict__ w3, const float* __restrict__ b3,
                    const float* __restrict__ wmu, const float* __restrict__ bmu,
                    float* __restrict__ out)
{
    // activations (f16 hi/lo), XOR-chunk swizzle: (row,k) -> row*256 + ((k>>3 ^ (row&31))<<3) + (k&7)
    __shared__ __align__(16) f16 hA_hi[M*256];   // 65536 B
    __shared__ __align__(16) f16 hA_lo[M*256];   // 65536 B -> 128 KB total, 1 block/CU
    // L4 partials overlay in hA_hi rows 64..71 (only touched between B6 and next L1 writeback)
    float* paL = (float*)(hA_hi + 16384);        // [4 cq][2 c][128 row] = 4096 B

    const int t  = threadIdx.x;
    const int l  = t & 63;
    const int wv = t >> 6;         // 8 waves
    const int lr = l & 15;
    const int q  = l >> 4;
    const int rh = wv & 1;         // rows [64*rh, 64*rh+64)
    const int cq = wv >> 1;        // cols [64*cq, 64*cq+64)

    float b1r[4], b2r[4], b3r[4], wmur[4][2];
    #pragma unroll
    for (int nt = 0; nt < 4; ++nt) {
        int col = 64*cq + 16*nt + lr;
        b1r[nt] = b1[col]; b2r[nt] = b2[col]; b3r[nt] = b3[col];
        wmur[nt][0] = wmu[2*col]; wmur[nt][1] = wmu[2*col + 1];
    }
    const float bm0 = bmu[0], bm1 = bmu[1];

    // w1 B-frags hoisted (step-invariant)
    f16x8 w1h[4], w1l[4];
    #pragma unroll
    for (int nt = 0; nt < 4; ++nt) {
        int n = 64*cq + 16*nt + lr;
        #pragma unroll
        for (int j = 0; j < 8; ++j) {
            int k = q*8 + j;
            float v = (k < 13) ? w1[k*256 + n] : 0.f;
            f16 h = (f16)v;
            w1h[nt][j] = h;
            w1l[nt][j] = (f16)(v - (float)h);
        }
    }

    float px=0.f, py=0.f, wx=0.f, wy=0.f;
    float mx_s=-1e30f, sum_s=0.f, mx_r=-1e30f, sum_r=0.f;
    if (t < M) {
        int g = blockIdx.x*M + t;
        px = pos0[2*g]; py = pos0[2*g+1]; wx = wind[2*g]; wy = wind[2*g+1];
    }

    float F[2][32];        // B-frag prefetch ping-pong (2 chunks in flight)
    f32x4 acc[4][4];

    // ---- priming: F <- w2 chunks 0,1; obs(step 0) ----
    FETCH_B(w2, 0, F[0]);
    FETCH_B(w2, 1, F[1]);
    if (t < M) { OBS_WRITE(); }

    for (int step = 0; step < HORIZON; ++step) {
        __syncthreads();   // B1: obs visible; paL consumed

        // ---- L1: obs(13 pad 32) x w1 -> acc ----
        INIT_ACC(b1r);
        {
            f16x8 ah[4], al[4];
            #pragma unroll
            for (int mt = 0; mt < 4; ++mt) {
                int off = (64*rh + 16*mt + lr)*40 + q*8;
                ah[mt] = *(const f16x8*)(hA_hi + off);
                al[mt] = *(const f16x8*)(hA_lo + off);
            }
            #pragma unroll
            for (int nt = 0; nt < 4; ++nt)
              #pragma unroll
              for (int mt = 0; mt < 4; ++mt)
                mfma3(acc[mt][nt], ah[mt], al[mt], w1h[nt], w1l[nt]);
        }
        __syncthreads();   // B2: obs reads done -> hA writable
        WRITEBACK_ACC();   // h1 -> hA
        INIT_ACC(b2r);
        __syncthreads();   // B3: h1 visible

        // ---- L2: 8 chunks, no internal barriers; B streams global->reg ----
        #pragma unroll
        for (int g = 0; g < 8; ++g) {
            f16x8 bh[4], bl[4], ah[4], al[4];
            CONV_B(F[g & 1], bh, bl);                   // waits only this chunk's loads
            if (g < 6)      { FETCH_B(w2, g + 2, F[g & 1]); }
            else if (g == 6){ FETCH_B(w3, 0, F[0]); }
            else            { FETCH_B(w3, 1, F[1]); }
            #pragma unroll
            for (int mt = 0; mt < 4; ++mt) {
                int row = 64*rh + 16*mt + lr;
                int off = row*256 + (((g*4 + q) ^ (row & 31)) << 3);
                ah[mt] = *(const f16x8*)(hA_hi + off);
                al[mt] = *(const f16x8*)(hA_lo + off);
            }
            #pragma unroll
            for (int nt = 0; nt < 4; ++nt)
              #pragma unroll
              for (int mt = 0; mt < 4; ++mt)
                mfma3(acc[mt][nt], ah[mt], al[mt], bh[nt], bl[nt]);
        }
        __syncthreads();   // B4: h1 reads done
        WRITEBACK_ACC();   // h2 -> hA
        INIT_ACC(b3r);
        __syncthreads();   // B5: h2 visible

        // ---- L3: 8 chunks; tail prefetches next step's w2 c0,c1 ----
        #pragma unroll
        for (int g = 0; g < 8; ++g) {
            f16x8 bh[4], bl[4], ah[4], al[4];
            CONV_B(F[g & 1], bh, bl);
            if (g < 6)      { FETCH_B(w3, g + 2, F[g & 1]); }
            else if (g == 6){ FETCH_B(w2, 0, F[0]); }
            else            { FETCH_B(w2, 1, F[1]); }
            #pragma unroll
            for (int mt = 0; mt < 4; ++mt) {
                int row = 64*rh + 16*mt + lr;
                int off = row*256 + (((g*4 + q) ^ (row & 31)) << 3);
                ah[mt] = *(const f16x8*)(hA_hi + off);
                al[mt] = *(const f16x8*)(hA_lo + off);
            }
            #pragma unroll
            for (int nt = 0; nt < 4; ++nt)
              #pragma unroll
              for (int mt = 0; mt < 4; ++mt)
                mfma3(acc[mt][nt], ah[mt], al[mt], bh[nt], bl[nt]);
        }

        // ---- fused L4: partials from relu(acc=h3), registers + shuffles ----
        float pa[4][4][2];
        #pragma unroll
        for (int mt = 0; mt < 4; ++mt)
          #pragma unroll
          for (int r = 0; r < 4; ++r)
            { pa[mt][r][0] = 0.f; pa[mt][r][1] = 0.f; }
        #pragma unroll
        for (int mt = 0; mt < 4; ++mt)
          #pragma unroll
          for (int nt = 0; nt < 4; ++nt)
            #pragma unroll
            for (int r = 0; r < 4; ++r) {
                float h = fmaxf(acc[mt][nt][r], 0.f);
                pa[mt][r][0] = fmaf(h, wmur[nt][0], pa[mt][r][0]);
                pa[mt][r][1] = fmaf(h, wmur[nt][1], pa[mt][r][1]);
            }
        #pragma unroll
        for (int s = 0; s < 4; ++s)
            #pragma unroll
            for (int mt = 0; mt < 4; ++mt)
              #pragma unroll
              for (int r = 0; r < 4; ++r) {
                  pa[mt][r][0] += __shfl_xor(pa[mt][r][0], 1 << s, 64);
                  pa[mt][r][1] += __shfl_xor(pa[mt][r][1], 1 << s, 64);
              }
        __syncthreads();   // B6: all hA (h2) reads done -> paL region writable
        if (lr == 0) {
            #pragma unroll
            for (int mt = 0; mt < 4; ++mt)
              #pragma unroll
              for (int c = 0; c < 2; ++c) {
                  f32x4 v = {pa[mt][0][c], pa[mt][1][c], pa[mt][2][c], pa[mt][3][c]};
                  *(f32x4*)&paL[(cq*2 + c)*128 + 64*rh + 16*mt + 4*q] = v;
              }
        }
        __syncthreads();   // B7: paL visible

        // ---- P5 + P0: action, dynamics, STREL, next obs ----
        if (t < M) {
            float s0 = bm0 + paL[0*128 + t] + paL[2*128 + t] + paL[4*128 + t] + paL[6*128 + t];
            float s1 = bm1 + paL[1*128 + t] + paL[3*128 + t] + paL[5*128 + t] + paL[7*128 + t];
            float ax = fminf(fmaxf(s0, -1.f), 1.f);
            float ay = fminf(fmaxf(s1, -1.f), 1.f);
            float vx = 2.f*ax + wx, vy = 2.f*ay + wy;
            #pragma unroll
            for (int s = 0; s < 4; ++s) {
                px = fminf(fmaxf(px + 0.0625f*vx, -4.f), 10.f);
                py = fminf(fmaxf(py + 0.0625f*vy, -4.f), 10.f);
            }
            float dx0 = px - 1.75f, dy0 = py - 1.75f;
            float dx1 = px - 1.75f, dy1 = py - 3.75f;
            float dx2 = px - 3.75f, dy2 = py - 2.00f;
            float c0 = sqrtf(dx0*dx0+dy0*dy0+1e-9f) - 0.38f;
            float c1 = sqrtf(dx1*dx1+dy1*dy1+1e-9f) - 0.42f;
            float c2 = sqrtf(dx2*dx2+dy2*dy2+1e-9f) - 0.34f;
            float cmin = fminf(c0, fminf(c1, c2));
            float ssum = expf(-50.f*(c0-cmin)) + expf(-50.f*(c1-cmin)) + expf(-50.f*(c2-cmin));
            float safe = cmin - logf(ssum)/50.f;
            float gdx = px - 4.f, gdy = py - 3.f;
            float reach = 0.45f - sqrtf(gdx*gdx+gdy*gdy+1e-9f);
            float xs = -8.f*safe;
            if (xs > mx_s) { sum_s = sum_s*expf(mx_s - xs) + 1.f; mx_s = xs; }
            else           { sum_s += expf(xs - mx_s); }
            float xr = 8.f*reach;
            if (xr > mx_r) { sum_r = sum_r*expf(mx_r - xr) + 1.f; mx_r = xr; }
            else           { sum_r += expf(xr - mx_r); }
            OBS_WRITE();   // obs for next step
        }
    }

    if (t < M) {
        float rs = -(mx_s + logf(sum_s)) * 0.125f;
        float rr =  (mx_r + logf(sum_r)) * 0.125f;
        float u0 = -8.f*rs, u1 = -8.f*rr;
        float mu = fmaxf(u0, u1);
        float rho = -(mu + logf(expf(u0-mu) + expf(u1-mu))) * 0.125f;
        out[blockIdx.x*M + t] = rho;
    }
}

} // namespace

extern "C" void kernel_launch(void* const* d_in, const int* in_sizes, int n_in,
                              void* d_out, int out_size, void* d_ws, size_t ws_size,
                              hipStream_t stream)
{
    const float* pos0 = (const float*)d_in[0];
    const float* wind = (const float*)d_in[1];
    const float* w1   = (const float*)d_in[2];
    const float* b1   = (const float*)d_in[3];
    const float* w2   = (const float*)d_in[4];
    const float* b2   = (const float*)d_in[5];
    const float* w3   = (const float*)d_in[6];
    const float* b3   = (const float*)d_in[7];
    const float* wmu  = (const float*)d_in[8];
    const float* bmu  = (const float*)d_in[9];
    float* out = (float*)d_out;
    (void)d_ws; (void)ws_size;

    const int B = in_sizes[0] / 2;     // 32768 agents
    const int blocks = B / M;          // 256 blocks, 1/CU
    rollout_kernel<<<blocks, NT, 0, stream>>>(pos0, wind, w1, b1, w2, b2,
                                              w3, b3, wmu, bmu, out);
}

// Round 7
// 4965.831 us; speedup vs baseline: 1.4201x; 1.4201x over previous
//
#include <hip/hip_runtime.h>
#include <math.h>

typedef _Float16 f16;
typedef _Float16 f16x8 __attribute__((ext_vector_type(8)));
typedef float f32x4 __attribute__((ext_vector_type(4)));

namespace {

constexpr int NT = 256;     // 4 waves -> 1 wave/SIMD possible -> 512-VGPR budget
constexpr int M  = 64;      // agents per block
constexpr int HORIZON = 64;

__device__ __forceinline__ void mfma3(f32x4& acc, f16x8 ah, f16x8 al, f16x8 bh, f16x8 bl)
{
    acc = __builtin_amdgcn_mfma_f32_16x16x32_f16(ah, bh, acc, 0, 0, 0);
    acc = __builtin_amdgcn_mfma_f32_16x16x32_f16(al, bh, acc, 0, 0, 0);
    acc = __builtin_amdgcn_mfma_f32_16x16x32_f16(ah, bl, acc, 0, 0, 0);
}

// fetch this wave's B-fragment fp32s for one 32-K chunk (32 dwords/thread)
#define FETCH_B(Wp, kc, Fv) do {                                             \
    _Pragma("unroll")                                                        \
    for (int _nt = 0; _nt < 4; ++_nt) {                                      \
        const float* _p = (Wp) + ((kc)*32 + q*8)*256 + 64*cq + 16*_nt + lr;  \
        _Pragma("unroll")                                                    \
        for (int _j = 0; _j < 8; ++_j) (Fv)[_nt*8 + _j] = _p[_j*256];        \
    }                                                                        \
} while (0)

// relu + hi/lo split of acc tile into swizzled hA
#define WRITEBACK_ACC() do {                                                 \
    _Pragma("unroll")                                                        \
    for (int _mt = 0; _mt < 4; ++_mt) {                                      \
      _Pragma("unroll")                                                      \
      for (int _nt = 0; _nt < 4; ++_nt) {                                    \
        _Pragma("unroll")                                                    \
        for (int _r = 0; _r < 4; ++_r) {                                     \
            float _h = fmaxf(acc[_mt][_nt][_r], 0.f);                        \
            f16 _hi = (f16)_h;                                               \
            f16 _lo = (f16)(_h - (float)_hi);                                \
            int _row = 16*_mt + 4*q + _r;                                    \
            int _col = 64*cq + 16*_nt + lr;                                  \
            int _off = _row*256 + (((_col >> 3) ^ (_row & 31)) << 3) + (_col & 7); \
            hA_hi[_off] = _hi;                                               \
            hA_lo[_off] = _lo;                                               \
        }                                                                    \
      }                                                                      \
    }                                                                        \
} while (0)

#define INIT_ACC(brv) do {                                                   \
    _Pragma("unroll")                                                        \
    for (int _mt = 0; _mt < 4; ++_mt)                                        \
      _Pragma("unroll")                                                      \
      for (int _nt = 0; _nt < 4; ++_nt)                                      \
        acc[_mt][_nt] = (f32x4){(brv)[_nt], (brv)[_nt], (brv)[_nt], (brv)[_nt]}; \
} while (0)

// one K-chunk of a 256-K GEMM: convert B per-nt (tiny live range) + MFMA
#define GEMM_CHUNK(Fv, g) do {                                               \
    f16x8 _ah[4], _al[4];                                                    \
    _Pragma("unroll")                                                        \
    for (int _mt = 0; _mt < 4; ++_mt) {                                      \
        int _row = 16*_mt + lr;                                              \
        int _off = _row*256 + ((((g)*4 + q) ^ (_row & 31)) << 3);            \
        _ah[_mt] = *(const f16x8*)(hA_hi + _off);                            \
        _al[_mt] = *(const f16x8*)(hA_lo + _off);                            \
    }                                                                        \
    _Pragma("unroll")                                                        \
    for (int _nt = 0; _nt < 4; ++_nt) {                                      \
        f16x8 _bh, _bl;                                                      \
        _Pragma("unroll")                                                    \
        for (int _j = 0; _j < 8; ++_j) {                                     \
            float _v = (Fv)[_nt*8 + _j];                                     \
            f16 _h = (f16)_v;                                                \
            _bh[_j] = _h;                                                    \
            _bl[_j] = (f16)(_v - (float)_h);                                 \
        }                                                                    \
        _Pragma("unroll")                                                    \
        for (int _mt = 0; _mt < 4; ++_mt)                                    \
            mfma3(acc[_mt][_nt], _ah[_mt], _al[_mt], _bh, _bl);              \
    }                                                                        \
} while (0)

// observation write for agent thread t (< M): 32 f16 hi/lo, stride-40 rows
#define OBS_WRITE() do {                                                     \
    float _o[32];                                                            \
    float _dx0 = px - 1.75f, _dy0 = py - 1.75f;                              \
    float _dx1 = px - 1.75f, _dy1 = py - 3.75f;                              \
    float _dx2 = px - 3.75f, _dy2 = py - 2.00f;                              \
    _o[0] = px*0.1f;        _o[1] = py*0.1f;                                 \
    _o[2] = (4.f-px)*0.1f;  _o[3] = (3.f-py)*0.1f;                           \
    _o[4] = -_dx0*0.1f;     _o[5] = -_dy0*0.1f;                              \
    _o[6] = -_dx1*0.1f;     _o[7] = -_dy1*0.1f;                              \
    _o[8] = -_dx2*0.1f;     _o[9] = -_dy2*0.1f;                              \
    _o[10] = sqrtf(_dx0*_dx0+_dy0*_dy0+1e-9f) - 0.38f;                       \
    _o[11] = sqrtf(_dx1*_dx1+_dy1*_dy1+1e-9f) - 0.42f;                       \
    _o[12] = sqrtf(_dx2*_dx2+_dy2*_dy2+1e-9f) - 0.34f;                       \
    _Pragma("unroll")                                                        \
    for (int _k = 13; _k < 32; ++_k) _o[_k] = 0.f;                           \
    _Pragma("unroll")                                                        \
    for (int _c = 0; _c < 4; ++_c) {                                         \
        f16x8 _hi, _lo;                                                      \
        _Pragma("unroll")                                                    \
        for (int _j = 0; _j < 8; ++_j) {                                     \
            float _v = _o[_c*8 + _j];                                        \
            f16 _h = (f16)_v;                                                \
            _hi[_j] = _h; _lo[_j] = (f16)(_v - (float)_h);                   \
        }                                                                    \
        *(f16x8*)(hA_hi + t*40 + _c*8) = _hi;                                \
        *(f16x8*)(hA_lo + t*40 + _c*8) = _lo;                                \
    }                                                                        \
} while (0)

__global__ __launch_bounds__(NT, 1)   // 1 wave/EU min -> up to 512 VGPRs, no spill
void rollout_kernel(const float* __restrict__ pos0, const float* __restrict__ wind,
                    const float* __restrict__ w1, const float* __restrict__ b1,
                    const float* __restrict__ w2, const float* __restrict__ b2,
                    const float* __restrict__ w3, const float* __restrict__ b3,
                    const float* __restrict__ wmu, const float* __restrict__ bmu,
                    float* __restrict__ out)
{
    // activations (f16 hi/lo), XOR-chunk swizzle: (row,k) -> row*256 + ((k>>3 ^ (row&31))<<3) + (k&7)
    __shared__ __align__(16) f16 hA_hi[M*256];   // 32 KB
    __shared__ __align__(16) f16 hA_lo[M*256];   // 32 KB
    // L4 partials overlay at hA_hi[8192..] (dead between B6 and next L1 writeback)
    float* paL = (float*)(hA_hi + 8192);         // [4 cq][2 c][64 row] = 2 KB

    const int t  = threadIdx.x;
    const int l  = t & 63;
    const int cq = t >> 6;         // wave id = col quarter: cols [64cq, 64cq+64)
    const int lr = l & 15;
    const int q  = l >> 4;

    float b1r[4], b2r[4], b3r[4], wmur[4][2];
    #pragma unroll
    for (int nt = 0; nt < 4; ++nt) {
        int col = 64*cq + 16*nt + lr;
        b1r[nt] = b1[col]; b2r[nt] = b2[col]; b3r[nt] = b3[col];
        wmur[nt][0] = wmu[2*col]; wmur[nt][1] = wmu[2*col + 1];
    }
    const float bm0 = bmu[0], bm1 = bmu[1];

    // w1 B-frags hoisted (step-invariant)
    f16x8 w1h[4], w1l[4];
    #pragma unroll
    for (int nt = 0; nt < 4; ++nt) {
        int n = 64*cq + 16*nt + lr;
        #pragma unroll
        for (int j = 0; j < 8; ++j) {
            int k = q*8 + j;
            float v = (k < 13) ? w1[k*256 + n] : 0.f;
            f16 h = (f16)v;
            w1h[nt][j] = h;
            w1l[nt][j] = (f16)(v - (float)h);
        }
    }

    float px=0.f, py=0.f, wx=0.f, wy=0.f;
    float mx_s=-1e30f, sum_s=0.f, mx_r=-1e30f, sum_r=0.f;
    if (t < M) {
        int g = blockIdx.x*M + t;
        px = pos0[2*g]; py = pos0[2*g+1]; wx = wind[2*g]; wy = wind[2*g+1];
    }

    float F[2][32];        // B-frag prefetch ping-pong (2 chunks in flight, regs)
    f32x4 acc[4][4];

    // ---- priming: F <- w2 chunks 0,1; obs(step 0) ----
    FETCH_B(w2, 0, F[0]);
    FETCH_B(w2, 1, F[1]);
    if (t < M) { OBS_WRITE(); }

    for (int step = 0; step < HORIZON; ++step) {
        __syncthreads();   // B1: obs visible; paL consumed

        // ---- L1: obs(13 pad 32) x w1 -> acc ----
        INIT_ACC(b1r);
        {
            f16x8 ah[4], al[4];
            #pragma unroll
            for (int mt = 0; mt < 4; ++mt) {
                int off = (16*mt + lr)*40 + q*8;
                ah[mt] = *(const f16x8*)(hA_hi + off);
                al[mt] = *(const f16x8*)(hA_lo + off);
            }
            #pragma unroll
            for (int nt = 0; nt < 4; ++nt)
              #pragma unroll
              for (int mt = 0; mt < 4; ++mt)
                mfma3(acc[mt][nt], ah[mt], al[mt], w1h[nt], w1l[nt]);
        }
        __syncthreads();   // B2: obs reads done -> hA writable
        WRITEBACK_ACC();   // h1 -> hA
        INIT_ACC(b2r);
        __syncthreads();   // B3: h1 visible

        // ---- L2: 8 chunks, no internal barriers; B streams global->reg ----
        #pragma unroll
        for (int g = 0; g < 8; ++g) {
            GEMM_CHUNK(F[g & 1], g);               // consumes chunk g
            if (g < 6)      { FETCH_B(w2, g + 2, F[g & 1]); }
            else if (g == 6){ FETCH_B(w3, 0, F[0]); }
            else            { FETCH_B(w3, 1, F[1]); }
        }
        __syncthreads();   // B4: h1 reads done
        WRITEBACK_ACC();   // h2 -> hA
        INIT_ACC(b3r);
        __syncthreads();   // B5: h2 visible

        // ---- L3: 8 chunks; tail prefetches next step's w2 c0,c1 ----
        #pragma unroll
        for (int g = 0; g < 8; ++g) {
            GEMM_CHUNK(F[g & 1], g);
            if (g < 6)      { FETCH_B(w3, g + 2, F[g & 1]); }
            else if (g == 6){ FETCH_B(w2, 0, F[0]); }
            else            { FETCH_B(w2, 1, F[1]); }
        }

        // ---- fused L4: partials from relu(acc=h3), registers + shuffles ----
        float pa[4][4][2];
        #pragma unroll
        for (int mt = 0; mt < 4; ++mt)
          #pragma unroll
          for (int r = 0; r < 4; ++r)
            { pa[mt][r][0] = 0.f; pa[mt][r][1] = 0.f; }
        #pragma unroll
        for (int mt = 0; mt < 4; ++mt)
          #pragma unroll
          for (int nt = 0; nt < 4; ++nt)
            #pragma unroll
            for (int r = 0; r < 4; ++r) {
                float h = fmaxf(acc[mt][nt][r], 0.f);
                pa[mt][r][0] = fmaf(h, wmur[nt][0], pa[mt][r][0]);
                pa[mt][r][1] = fmaf(h, wmur[nt][1], pa[mt][r][1]);
            }
        #pragma unroll
        for (int s = 0; s < 4; ++s)
            #pragma unroll
            for (int mt = 0; mt < 4; ++mt)
              #pragma unroll
              for (int r = 0; r < 4; ++r) {
                  pa[mt][r][0] += __shfl_xor(pa[mt][r][0], 1 << s, 64);
                  pa[mt][r][1] += __shfl_xor(pa[mt][r][1], 1 << s, 64);
              }
        __syncthreads();   // B6: all hA (h2) reads done -> paL region writable
        if (lr == 0) {
            #pragma unroll
            for (int mt = 0; mt < 4; ++mt)
              #pragma unroll
              for (int c = 0; c < 2; ++c) {
                  f32x4 v = {pa[mt][0][c], pa[mt][1][c], pa[mt][2][c], pa[mt][3][c]};
                  *(f32x4*)&paL[(cq*2 + c)*64 + 16*mt + 4*q] = v;
              }
        }
        __syncthreads();   // B7: paL visible

        // ---- P5 + P0: action, dynamics, STREL, next obs ----
        if (t < M) {
            float s0 = bm0 + paL[0*64 + t] + paL[2*64 + t] + paL[4*64 + t] + paL[6*64 + t];
            float s1 = bm1 + paL[1*64 + t] + paL[3*64 + t] + paL[5*64 + t] + paL[7*64 + t];
            float ax = fminf(fmaxf(s0, -1.f), 1.f);
            float ay = fminf(fmaxf(s1, -1.f), 1.f);
            float vx = 2.f*ax + wx, vy = 2.f*ay + wy;
            #pragma unroll
            for (int s = 0; s < 4; ++s) {
                px = fminf(fmaxf(px + 0.0625f*vx, -4.f), 10.f);
                py = fminf(fmaxf(py + 0.0625f*vy, -4.f), 10.f);
            }
            float dx0 = px - 1.75f, dy0 = py - 1.75f;
            float dx1 = px - 1.75f, dy1 = py - 3.75f;
            float dx2 = px - 3.75f, dy2 = py - 2.00f;
            float c0 = sqrtf(dx0*dx0+dy0*dy0+1e-9f) - 0.38f;
            float c1 = sqrtf(dx1*dx1+dy1*dy1+1e-9f) - 0.42f;
            float c2 = sqrtf(dx2*dx2+dy2*dy2+1e-9f) - 0.34f;
            float cmin = fminf(c0, fminf(c1, c2));
            float ssum = expf(-50.f*(c0-cmin)) + expf(-50.f*(c1-cmin)) + expf(-50.f*(c2-cmin));
            float safe = cmin - logf(ssum)/50.f;
            float gdx = px - 4.f, gdy = py - 3.f;
            float reach = 0.45f - sqrtf(gdx*gdx+gdy*gdy+1e-9f);
            float xs = -8.f*safe;
            if (xs > mx_s) { sum_s = sum_s*expf(mx_s - xs) + 1.f; mx_s = xs; }
            else           { sum_s += expf(xs - mx_s); }
            float xr = 8.f*reach;
            if (xr > mx_r) { sum_r = sum_r*expf(mx_r - xr) + 1.f; mx_r = xr; }
            else           { sum_r += expf(xr - mx_r); }
            OBS_WRITE();   // obs for next step
        }
    }

    if (t < M) {
        float rs = -(mx_s + logf(sum_s)) * 0.125f;
        float rr =  (mx_r + logf(sum_r)) * 0.125f;
        float u0 = -8.f*rs, u1 = -8.f*rr;
        float mu = fmaxf(u0, u1);
        float rho = -(mu + logf(expf(u0-mu) + expf(u1-mu))) * 0.125f;
        out[blockIdx.x*M + t] = rho;
    }
}

} // namespace

extern "C" void kernel_launch(void* const* d_in, const int* in_sizes, int n_in,
                              void* d_out, int out_size, void* d_ws, size_t ws_size,
                              hipStream_t stream)
{
    const float* pos0 = (const float*)d_in[0];
    const float* wind = (const float*)d_in[1];
    const float* w1   = (const float*)d_in[2];
    const float* b1   = (const float*)d_in[3];
    const float* w2   = (const float*)d_in[4];
    const float* b2   = (const float*)d_in[5];
    const float* w3   = (const float*)d_in[6];
    const float* b3   = (const float*)d_in[7];
    const float* wmu  = (const float*)d_in[8];
    const float* bmu  = (const float*)d_in[9];
    float* out = (float*)d_out;
    (void)d_ws; (void)ws_size;

    const int B = in_sizes[0] / 2;     // 32768 agents
    const int blocks = B / M;          // 512 blocks
    rollout_kernel<<<blocks, NT, 0, stream>>>(pos0, wind, w1, b1, w2, b2,
                                              w3, b3, wmu, bmu, out);
}